// Round 11
// baseline (746.793 us; speedup 1.0000x reference)
//
#include <hip/hip_runtime.h>

#define N_NODES 50000
#define N_EDGES 800000
#define D_FEAT 128
#define LN_EPS 1e-5f
#define TM 32          // nodes per block in gsage_main
#define KB 32          // K-chunk
#define APAD 36        // padded A-tile row stride (floats)
#define NBLK 196       // ceil(N_NODES/256) scan blocks
#define CVT_B 3125     // blocks for cvt range (800000 threads)
#define HIST_B 3125    // blocks for hist range

__device__ __forceinline__ unsigned short f2bf(float f) {
    union { float f; unsigned int i; } v; v.f = f;
    unsigned int x = v.i;
    unsigned int lsb = (x >> 16) & 1u;
    x += 0x7fffu + lsb;          // RNE
    return (unsigned short)(x >> 16);
}
__device__ __forceinline__ float bflo(unsigned int u) {
    union { unsigned int i; float f; } v; v.i = u << 16; return v.f;
}
__device__ __forceinline__ float bfhi(unsigned int u) {
    union { unsigned int i; float f; } v; v.i = u & 0xffff0000u; return v.f;
}

// ---------------------------------------------------------------------------
// prep kernel: block-range-split union of
//   [0, CVT_B)                  : x fp32 -> xh bf16-packed
//   [CVT_B, CVT_B+HIST_B)       : histogram of dst into deg_cnt AND bsum(>>8)
//   [CVT_B+HIST_B, +128)        : wprep row t (fused weight + cvec)
// ---------------------------------------------------------------------------
__global__ void prep_kernel(const float* __restrict__ x,
                            const int* __restrict__ ei,
                            const float* __restrict__ agg_W,
                            const float* __restrict__ agg_b,
                            const float* __restrict__ W,
                            const float* __restrict__ b,
                            unsigned int* __restrict__ xh,
                            int* __restrict__ deg_cnt,
                            int* __restrict__ bsum,
                            float* __restrict__ Wt2,
                            float* __restrict__ cvec)
{
    int blk = blockIdx.x;
    if (blk < CVT_B) {
        int i = blk * 256 + threadIdx.x;      // 800000 threads, 8 floats each
        const float4 a = *(const float4*)(x + (size_t)i * 8);
        const float4 c = *(const float4*)(x + (size_t)i * 8 + 4);
        uint4 o;
        o.x = ((unsigned)f2bf(a.y) << 16) | f2bf(a.x);
        o.y = ((unsigned)f2bf(a.w) << 16) | f2bf(a.z);
        o.z = ((unsigned)f2bf(c.y) << 16) | f2bf(c.x);
        o.w = ((unsigned)f2bf(c.w) << 16) | f2bf(c.z);
        *(uint4*)(xh + (size_t)i * 4) = o;
    } else if (blk < CVT_B + HIST_B) {
        int e = (blk - CVT_B) * 256 + threadIdx.x;
        if (e < N_EDGES) {
            int dst = ei[N_EDGES + e];
            dst = (dst < 0) ? 0 : ((dst >= N_NODES) ? (N_NODES - 1) : dst);
            atomicAdd(&deg_cnt[dst], 1);
            atomicAdd(&bsum[dst >> 8], 1);    // per-256-chunk sum for the scan
        }
    } else {
        int t = blk - CVT_B - HIST_B;         // 0..127 (Wt2 row)
        int n = threadIdx.x;
        if (n < 128) {
            Wt2[t * 128 + n] = W[t * 128 + n];            // W1 half
            float m = 0.0f;
            for (int j = 0; j < 128; ++j)
                m += agg_W[t * 128 + j] * W[(128 + j) * 128 + n];
            Wt2[(128 + t) * 128 + n] = m;
            if (t == 0) {
                float s = b[n];
                for (int j = 0; j < 128; ++j)
                    s += agg_b[j] * W[(128 + j) * 128 + n];
                cvec[n] = s;
            }
        }
    }
}

// ---------------------------------------------------------------------------
// exclusive scan of the 196 chunk sums (single small block)
// ---------------------------------------------------------------------------
__global__ void scanblk_kernel(const int* __restrict__ bsum, int* __restrict__ boff)
{
    __shared__ int s[256];
    int t = threadIdx.x;
    int v = (t < NBLK) ? bsum[t] : 0;
    s[t] = v;
    __syncthreads();
    for (int off = 1; off < 256; off <<= 1) {
        int u = (t >= off) ? s[t - off] : 0;
        __syncthreads();
        s[t] += u;
        __syncthreads();
    }
    if (t < NBLK) boff[t] = s[t] - v;   // exclusive
}

// ---------------------------------------------------------------------------
// block-local exclusive scan + block offset -> pos
// ---------------------------------------------------------------------------
__global__ void scanpos_kernel(const int* __restrict__ deg_cnt,
                               const int* __restrict__ boff,
                               int* __restrict__ pos)
{
    __shared__ int s[256];
    int b = blockIdx.x, t = threadIdx.x;
    int i = b * 256 + t;
    int v = (i < N_NODES) ? deg_cnt[i] : 0;
    s[t] = v;
    __syncthreads();
    for (int off = 1; off < 256; off <<= 1) {
        int u = (t >= off) ? s[t - off] : 0;
        __syncthreads();
        s[t] += u;
        __syncthreads();
    }
    if (i < N_NODES) pos[i] = boff[b] + s[t] - v;   // exclusive global
}

// ---------------------------------------------------------------------------
__global__ void fill_kernel(const int* __restrict__ ei, int* __restrict__ pos,
                            int* __restrict__ edge_src)
{
    int e = blockIdx.x * 256 + threadIdx.x;
    if (e >= N_EDGES) return;
    int src = ei[e];
    int dst = ei[N_EDGES + e];
    src = (src < 0) ? 0 : ((src >= N_NODES) ? (N_NODES - 1) : src);
    dst = (dst < 0) ? 0 : ((dst >= N_NODES) ? (N_NODES - 1) : dst);
    int slot = atomicAdd(&pos[dst], 1);
    edge_src[slot] = src;
}

// ---------------------------------------------------------------------------
// gather: one wave per node, 4 edges per iteration (quarter-wave per edge,
// uint4 = 8 bf16 feats per lane). agg mean (fp32) written into d_out scratch.
// ---------------------------------------------------------------------------
__global__ void gather_kernel(const uint4* __restrict__ xh,   // 16 uint4 per row
                              const int* __restrict__ pos,    // = end after fill
                              const int* __restrict__ deg_cnt,
                              const int* __restrict__ edge_src,
                              float* __restrict__ agg)        // d_out scratch
{
    int tid  = threadIdx.x;
    int node = blockIdx.x * 4 + (tid >> 6);
    int lane = tid & 63;
    int quarter = lane >> 4;     // 0..3  (edge slot within iteration)
    int sub     = lane & 15;     // 0..15 (uint4 within row)
    if (node >= N_NODES) return;

    int end   = pos[node];
    int dcnt  = deg_cnt[node];
    int start = end - dcnt;

    float a0 = 0.f, a1 = 0.f, a2 = 0.f, a3 = 0.f,
          a4 = 0.f, a5 = 0.f, a6 = 0.f, a7 = 0.f;

    for (int b = start; b < end; b += 64) {
        int nb = end - b; if (nb > 64) nb = 64;
        int sid = (b + lane < end) ? edge_src[b + lane] : 0;
        for (int j = 0; j < nb; j += 4) {
            int eidx = j + quarter;
            int s = __shfl(sid, eidx, 64);
            if (eidx < nb) {
                const uint4 v = xh[(size_t)s * 16 + sub];
                a0 += bflo(v.x); a1 += bfhi(v.x);
                a2 += bflo(v.y); a3 += bfhi(v.y);
                a4 += bflo(v.z); a5 += bfhi(v.z);
                a6 += bflo(v.w); a7 += bfhi(v.w);
            }
        }
    }
    #pragma unroll
    for (int m = 16; m <= 32; m <<= 1) {
        a0 += __shfl_xor(a0, m, 64); a1 += __shfl_xor(a1, m, 64);
        a2 += __shfl_xor(a2, m, 64); a3 += __shfl_xor(a3, m, 64);
        a4 += __shfl_xor(a4, m, 64); a5 += __shfl_xor(a5, m, 64);
        a6 += __shfl_xor(a6, m, 64); a7 += __shfl_xor(a7, m, 64);
    }
    if (quarter == 0) {
        float inv = 1.0f / (float)((dcnt > 1) ? dcnt : 1);
        float4 m0, m1;
        m0.x = a0 * inv; m0.y = a1 * inv; m0.z = a2 * inv; m0.w = a3 * inv;
        m1.x = a4 * inv; m1.y = a5 * inv; m1.z = a6 * inv; m1.w = a7 * inv;
        float* dst = agg + (size_t)node * D_FEAT + sub * 8;
        *(float4*)dst       = m0;
        *(float4*)(dst + 4) = m1;
    }
}

// ---------------------------------------------------------------------------
// fused GEMM (A=[x|agg] @ Wt2^T + c) -> ReLU -> LayerNorm -> out (fp32).
// TM=32 nodes/block, thread (tx=tid&31, ty=tid>>5) owns 4 nodes x 4 cols.
// Software-pipelined: double-buffered LDS (A+W), register prefetch of chunk
// c+1 issued before computing chunk c, ONE __syncthreads per chunk.
// Inner loop processes 4 k per step: 8 ds_read_b128 vs 64 FMAs -> VALU-bound.
// agg aliases out: each block reads only its own nodes' agg before writing.
// ---------------------------------------------------------------------------
__global__ __launch_bounds__(256) void gsage_main(
        const float* __restrict__ x,
        const float* __restrict__ agg,      // aliases `out`
        const float* __restrict__ Wt2,
        const float* __restrict__ cvec,
        const float* __restrict__ gamma,
        const float* __restrict__ beta,
        float* __restrict__ out)
{
    __shared__ float A[2][TM][APAD];   // 2 x 32 x 36 = 9.2 KB
    __shared__ float Wc[2][KB * 128];  // 2 x 16 KB

    int tid   = threadIdx.x;
    int tx    = tid & 31;
    int ty    = tid >> 5;
    int node0 = blockIdx.x * TM;

    // staging indices (fixed per thread)
    int ar  = tid >> 3;              // A row 0..31
    int akk = (tid & 7) * 4;         // A k-offset within chunk
    int anode = node0 + ar;

    float acc[4][4];
    #pragma unroll
    for (int i = 0; i < 4; ++i)
        #pragma unroll
        for (int j = 0; j < 4; ++j) acc[i][j] = 0.0f;

    // ---- prologue: stage chunk 0 directly ----
    {
        float4 v = make_float4(0.f, 0.f, 0.f, 0.f);
        if (anode < N_NODES)
            v = *(const float4*)(x + (size_t)anode * D_FEAT + akk);
        *(float4*)&A[0][ar][akk] = v;
        const float4* src = (const float4*)Wt2;
        float4* dst = (float4*)Wc[0];
        #pragma unroll
        for (int i = 0; i < 4; ++i)
            dst[i * 256 + tid] = src[i * 256 + tid];
    }
    __syncthreads();

    for (int c = 0; c < 8; ++c) {
        int cur = c & 1, nxt = cur ^ 1;

        // ---- issue prefetch of chunk c+1 into registers ----
        float4 pa = make_float4(0.f, 0.f, 0.f, 0.f);
        float4 pw0, pw1, pw2, pw3;
        if (c < 7) {
            int k0n = (c + 1) * KB;
            if (anode < N_NODES) {
                const float* srcp = (k0n < 128)
                    ? (x   + (size_t)anode * D_FEAT + k0n + akk)
                    : (agg + (size_t)anode * D_FEAT + (k0n - 128) + akk);
                pa = *(const float4*)srcp;
            }
            const float4* src = (const float4*)(Wt2 + k0n * 128);
            pw0 = src[0 * 256 + tid];
            pw1 = src[1 * 256 + tid];
            pw2 = src[2 * 256 + tid];
            pw3 = src[3 * 256 + tid];
        }

        // ---- compute chunk c ----
        const float* Ab = &A[cur][0][0];
        const float* Wb = Wc[cur];
        #pragma unroll
        for (int kq = 0; kq < 8; ++kq) {
            float4 a0 = *(const float4*)(Ab + (ty * 4 + 0) * APAD + kq * 4);
            float4 a1 = *(const float4*)(Ab + (ty * 4 + 1) * APAD + kq * 4);
            float4 a2 = *(const float4*)(Ab + (ty * 4 + 2) * APAD + kq * 4);
            float4 a3 = *(const float4*)(Ab + (ty * 4 + 3) * APAD + kq * 4);
            const float* wbase = Wb + (kq * 4) * 128 + tx * 4;
            float4 w;
#define FMA_STEP(AX0, AX1, AX2, AX3)                                           \
            acc[0][0] += (AX0)*w.x; acc[0][1] += (AX0)*w.y;                    \
            acc[0][2] += (AX0)*w.z; acc[0][3] += (AX0)*w.w;                    \
            acc[1][0] += (AX1)*w.x; acc[1][1] += (AX1)*w.y;                    \
            acc[1][2] += (AX1)*w.z; acc[1][3] += (AX1)*w.w;                    \
            acc[2][0] += (AX2)*w.x; acc[2][1] += (AX2)*w.y;                    \
            acc[2][2] += (AX2)*w.z; acc[2][3] += (AX2)*w.w;                    \
            acc[3][0] += (AX3)*w.x; acc[3][1] += (AX3)*w.y;                    \
            acc[3][2] += (AX3)*w.z; acc[3][3] += (AX3)*w.w;
            w = *(const float4*)(wbase + 0 * 128); FMA_STEP(a0.x, a1.x, a2.x, a3.x)
            w = *(const float4*)(wbase + 1 * 128); FMA_STEP(a0.y, a1.y, a2.y, a3.y)
            w = *(const float4*)(wbase + 2 * 128); FMA_STEP(a0.z, a1.z, a2.z, a3.z)
            w = *(const float4*)(wbase + 3 * 128); FMA_STEP(a0.w, a1.w, a2.w, a3.w)
#undef FMA_STEP
        }

        // ---- commit prefetch into the other buffer ----
        if (c < 7) {
            *(float4*)&A[nxt][ar][akk] = pa;
            float4* dst = (float4*)Wc[nxt];
            dst[0 * 256 + tid] = pw0;
            dst[1 * 256 + tid] = pw1;
            dst[2 * 256 + tid] = pw2;
            dst[3 * 256 + tid] = pw3;
        }
        __syncthreads();
    }

    // ---- epilogue: +c, ReLU, LayerNorm over 128 cols (32 tx lanes) ----
    float4 cv = *(const float4*)(cvec  + tx * 4);
    float4 gv = *(const float4*)(gamma + tx * 4);
    float4 bv = *(const float4*)(beta  + tx * 4);

    #pragma unroll
    for (int i = 0; i < 4; ++i) {
        float v0 = acc[i][0] + cv.x; v0 = (v0 > 0.f) ? v0 : 0.f;
        float v1 = acc[i][1] + cv.y; v1 = (v1 > 0.f) ? v1 : 0.f;
        float v2 = acc[i][2] + cv.z; v2 = (v2 > 0.f) ? v2 : 0.f;
        float v3 = acc[i][3] + cv.w; v3 = (v3 > 0.f) ? v3 : 0.f;
        float s1 = v0 + v1 + v2 + v3;
        float s2 = v0*v0 + v1*v1 + v2*v2 + v3*v3;
        #pragma unroll
        for (int m = 1; m < 32; m <<= 1) {
            s1 += __shfl_xor(s1, m, 64);
            s2 += __shfl_xor(s2, m, 64);
        }
        float mu   = s1 * (1.0f / 128.0f);
        float var  = s2 * (1.0f / 128.0f) - mu * mu;
        float rstd = rsqrtf(var + LN_EPS);
        int node = node0 + ty * 4 + i;
        if (node < N_NODES) {
            float4 o;
            o.x = (v0 - mu) * rstd * gv.x + bv.x;
            o.y = (v1 - mu) * rstd * gv.y + bv.y;
            o.z = (v2 - mu) * rstd * gv.z + bv.z;
            o.w = (v3 - mu) * rstd * gv.w + bv.w;
            *(float4*)(out + (size_t)node * D_FEAT + tx * 4) = o;
        }
    }
}

// ---------------------------------------------------------------------------
extern "C" void kernel_launch(void* const* d_in, const int* in_sizes, int n_in,
                              void* d_out, int out_size, void* d_ws, size_t ws_size,
                              hipStream_t stream) {
    const float* x     = (const float*)d_in[0];
    const int*   ei    = (const int*)d_in[1];
    const float* agg_W = (const float*)d_in[2];
    const float* agg_b = (const float*)d_in[3];
    const float* W     = (const float*)d_in[4];
    const float* b     = (const float*)d_in[5];
    const float* gamma = (const float*)d_in[6];
    const float* beta  = (const float*)d_in[7];
    float*       out   = (float*)d_out;

    size_t out_bytes = (size_t)out_size * sizeof(float);

    if (n_in != 8)                       { hipMemsetAsync(d_out, 0x45, out_bytes, stream); return; }
    if (in_sizes[0] != N_NODES * D_FEAT) { hipMemsetAsync(d_out, 0x48, out_bytes, stream); return; }
    if (in_sizes[1] != 2 * N_EDGES)      { hipMemsetAsync(d_out, 0x49, out_bytes, stream); return; }
    if (out_size != N_NODES * D_FEAT)    { hipMemsetAsync(d_out, 0x47, out_bytes, stream); return; }

    // workspace layout (4-byte elements) — deg_cnt and bsum adjacent => 1 memset
    int*   deg_cnt  = (int*)d_ws;                  // 50000
    int*   bsum     = deg_cnt + N_NODES;           // NBLK
    int*   boff     = bsum + NBLK;                 // NBLK
    int*   pos      = boff + NBLK;                 // 50000
    int*   edge_src = pos + N_NODES;               // 800000
    float* Wt2      = (float*)(edge_src + N_EDGES);// 256*128
    float* cvec     = Wt2 + 256 * 128;             // 128
    unsigned int* xh = (unsigned int*)(cvec + 128);// 50000*64 uints (bf16 x)
    size_t need_ws = ((size_t)N_NODES * 2 + N_EDGES + 256 * 128 + 128 + 2 * NBLK
                      + (size_t)N_NODES * 64) * 4;
    if (ws_size < need_ws)               { hipMemsetAsync(d_out, 0x46, out_bytes, stream); return; }

    hipMemsetAsync(deg_cnt, 0, (N_NODES + NBLK) * sizeof(int), stream);
    prep_kernel<<<CVT_B + HIST_B + 128, 256, 0, stream>>>(
        x, ei, agg_W, agg_b, W, b, xh, deg_cnt, bsum, Wt2, cvec);
    scanblk_kernel<<<1, 256, 0, stream>>>(bsum, boff);
    scanpos_kernel<<<NBLK, 256, 0, stream>>>(deg_cnt, boff, pos);
    fill_kernel<<<(N_EDGES + 255) / 256, 256, 0, stream>>>(ei, pos, edge_src);
    gather_kernel<<<(N_NODES + 3) / 4, 256, 0, stream>>>(
        (const uint4*)xh, pos, deg_cnt, edge_src, out);
    gsage_main<<<(N_NODES + TM - 1) / TM, 256, 0, stream>>>(
        x, out, Wt2, cvec, gamma, beta, out);
}

// Round 12
// 309.735 us; speedup vs baseline: 2.4111x; 2.4111x over previous
//
#include <hip/hip_runtime.h>

#define N_NODES 50000
#define N_EDGES 800000
#define D_FEAT 128
#define LN_EPS 1e-5f
#define TM 32          // nodes per block in gsage_main
#define KB 32          // K-chunk
#define APAD 36        // padded A-tile row stride (floats)
#define NBLK 196       // ceil(N_NODES/256) scan blocks
#define CVT_B 3125     // blocks for cvt range (800000 threads)
#define HIST_B 3125    // blocks for hist range

__device__ __forceinline__ unsigned short f2bf(float f) {
    union { float f; unsigned int i; } v; v.f = f;
    unsigned int x = v.i;
    unsigned int lsb = (x >> 16) & 1u;
    x += 0x7fffu + lsb;          // RNE
    return (unsigned short)(x >> 16);
}
__device__ __forceinline__ float bflo(unsigned int u) {
    union { unsigned int i; float f; } v; v.i = u << 16; return v.f;
}
__device__ __forceinline__ float bfhi(unsigned int u) {
    union { unsigned int i; float f; } v; v.i = u & 0xffff0000u; return v.f;
}

// ---------------------------------------------------------------------------
// prep kernel: block-range-split union of
//   [0, CVT_B)            : x fp32 -> xh bf16-packed
//   [CVT_B, CVT_B+HIST_B) : histogram of dst into deg_cnt ONLY
//                           (NO low-cardinality atomics — R11 lesson: 800K
//                           atomics on 196 addresses serialized ~400us)
//   [CVT_B+HIST_B, +128)  : wprep row t (fused weight + cvec)
// ---------------------------------------------------------------------------
__global__ void prep_kernel(const float* __restrict__ x,
                            const int* __restrict__ ei,
                            const float* __restrict__ agg_W,
                            const float* __restrict__ agg_b,
                            const float* __restrict__ W,
                            const float* __restrict__ b,
                            unsigned int* __restrict__ xh,
                            int* __restrict__ deg_cnt,
                            float* __restrict__ Wt2,
                            float* __restrict__ cvec)
{
    int blk = blockIdx.x;
    if (blk < CVT_B) {
        int i = blk * 256 + threadIdx.x;      // 800000 threads, 8 floats each
        const float4 a = *(const float4*)(x + (size_t)i * 8);
        const float4 c = *(const float4*)(x + (size_t)i * 8 + 4);
        uint4 o;
        o.x = ((unsigned)f2bf(a.y) << 16) | f2bf(a.x);
        o.y = ((unsigned)f2bf(a.w) << 16) | f2bf(a.z);
        o.z = ((unsigned)f2bf(c.y) << 16) | f2bf(c.x);
        o.w = ((unsigned)f2bf(c.w) << 16) | f2bf(c.z);
        *(uint4*)(xh + (size_t)i * 4) = o;
    } else if (blk < CVT_B + HIST_B) {
        int e = (blk - CVT_B) * 256 + threadIdx.x;
        if (e < N_EDGES) {
            int dst = ei[N_EDGES + e];
            dst = (dst < 0) ? 0 : ((dst >= N_NODES) ? (N_NODES - 1) : dst);
            atomicAdd(&deg_cnt[dst], 1);
        }
    } else {
        int t = blk - CVT_B - HIST_B;         // 0..127 (Wt2 row)
        int n = threadIdx.x;
        if (n < 128) {
            Wt2[t * 128 + n] = W[t * 128 + n];            // W1 half
            float m = 0.0f;
            for (int j = 0; j < 128; ++j)
                m += agg_W[t * 128 + j] * W[(128 + j) * 128 + n];
            Wt2[(128 + t) * 128 + n] = m;
            if (t == 0) {
                float s = b[n];
                for (int j = 0; j < 128; ++j)
                    s += agg_b[j] * W[(128 + j) * 128 + n];
                cvec[n] = s;
            }
        }
    }
}

// ---------------------------------------------------------------------------
// per-256-chunk sum of deg_cnt -> bsum (reduction, no atomics)
// ---------------------------------------------------------------------------
__global__ void blocksum_kernel(const int* __restrict__ deg_cnt, int* __restrict__ bsum)
{
    __shared__ int ws[4];
    int b = blockIdx.x, t = threadIdx.x;
    int i = b * 256 + t;
    int v = (i < N_NODES) ? deg_cnt[i] : 0;
    #pragma unroll
    for (int off = 1; off < 64; off <<= 1) v += __shfl_xor(v, off, 64);
    if ((t & 63) == 0) ws[t >> 6] = v;
    __syncthreads();
    if (t == 0) bsum[b] = ws[0] + ws[1] + ws[2] + ws[3];
}

// ---------------------------------------------------------------------------
// exclusive scan of the 196 chunk sums (single small block)
// ---------------------------------------------------------------------------
__global__ void scanblk_kernel(const int* __restrict__ bsum, int* __restrict__ boff)
{
    __shared__ int s[256];
    int t = threadIdx.x;
    int v = (t < NBLK) ? bsum[t] : 0;
    s[t] = v;
    __syncthreads();
    for (int off = 1; off < 256; off <<= 1) {
        int u = (t >= off) ? s[t - off] : 0;
        __syncthreads();
        s[t] += u;
        __syncthreads();
    }
    if (t < NBLK) boff[t] = s[t] - v;   // exclusive
}

// ---------------------------------------------------------------------------
// block-local exclusive scan + block offset -> pos
// ---------------------------------------------------------------------------
__global__ void scanpos_kernel(const int* __restrict__ deg_cnt,
                               const int* __restrict__ boff,
                               int* __restrict__ pos)
{
    __shared__ int s[256];
    int b = blockIdx.x, t = threadIdx.x;
    int i = b * 256 + t;
    int v = (i < N_NODES) ? deg_cnt[i] : 0;
    s[t] = v;
    __syncthreads();
    for (int off = 1; off < 256; off <<= 1) {
        int u = (t >= off) ? s[t - off] : 0;
        __syncthreads();
        s[t] += u;
        __syncthreads();
    }
    if (i < N_NODES) pos[i] = boff[b] + s[t] - v;   // exclusive global
}

// ---------------------------------------------------------------------------
__global__ void fill_kernel(const int* __restrict__ ei, int* __restrict__ pos,
                            int* __restrict__ edge_src)
{
    int e = blockIdx.x * 256 + threadIdx.x;
    if (e >= N_EDGES) return;
    int src = ei[e];
    int dst = ei[N_EDGES + e];
    src = (src < 0) ? 0 : ((src >= N_NODES) ? (N_NODES - 1) : src);
    dst = (dst < 0) ? 0 : ((dst >= N_NODES) ? (N_NODES - 1) : dst);
    int slot = atomicAdd(&pos[dst], 1);
    edge_src[slot] = src;
}

// ---------------------------------------------------------------------------
// gather: one wave per node, 4 edges per iteration (quarter-wave per edge,
// uint4 = 8 bf16 feats per lane). agg mean (fp32) written into d_out scratch.
// ---------------------------------------------------------------------------
__global__ void gather_kernel(const uint4* __restrict__ xh,   // 16 uint4 per row
                              const int* __restrict__ pos,    // = end after fill
                              const int* __restrict__ deg_cnt,
                              const int* __restrict__ edge_src,
                              float* __restrict__ agg)        // d_out scratch
{
    int tid  = threadIdx.x;
    int node = blockIdx.x * 4 + (tid >> 6);
    int lane = tid & 63;
    int quarter = lane >> 4;     // 0..3  (edge slot within iteration)
    int sub     = lane & 15;     // 0..15 (uint4 within row)
    if (node >= N_NODES) return;

    int end   = pos[node];
    int dcnt  = deg_cnt[node];
    int start = end - dcnt;

    float a0 = 0.f, a1 = 0.f, a2 = 0.f, a3 = 0.f,
          a4 = 0.f, a5 = 0.f, a6 = 0.f, a7 = 0.f;

    for (int b = start; b < end; b += 64) {
        int nb = end - b; if (nb > 64) nb = 64;
        int sid = (b + lane < end) ? edge_src[b + lane] : 0;
        for (int j = 0; j < nb; j += 4) {
            int eidx = j + quarter;
            int s = __shfl(sid, eidx, 64);
            if (eidx < nb) {
                const uint4 v = xh[(size_t)s * 16 + sub];
                a0 += bflo(v.x); a1 += bfhi(v.x);
                a2 += bflo(v.y); a3 += bfhi(v.y);
                a4 += bflo(v.z); a5 += bfhi(v.z);
                a6 += bflo(v.w); a7 += bfhi(v.w);
            }
        }
    }
    #pragma unroll
    for (int m = 16; m <= 32; m <<= 1) {
        a0 += __shfl_xor(a0, m, 64); a1 += __shfl_xor(a1, m, 64);
        a2 += __shfl_xor(a2, m, 64); a3 += __shfl_xor(a3, m, 64);
        a4 += __shfl_xor(a4, m, 64); a5 += __shfl_xor(a5, m, 64);
        a6 += __shfl_xor(a6, m, 64); a7 += __shfl_xor(a7, m, 64);
    }
    if (quarter == 0) {
        float inv = 1.0f / (float)((dcnt > 1) ? dcnt : 1);
        float4 m0, m1;
        m0.x = a0 * inv; m0.y = a1 * inv; m0.z = a2 * inv; m0.w = a3 * inv;
        m1.x = a4 * inv; m1.y = a5 * inv; m1.z = a6 * inv; m1.w = a7 * inv;
        float* dst = agg + (size_t)node * D_FEAT + sub * 8;
        *(float4*)dst       = m0;
        *(float4*)(dst + 4) = m1;
    }
}

// ---------------------------------------------------------------------------
// fused GEMM (A=[x|agg] @ Wt2^T + c) -> ReLU -> LayerNorm -> out (fp32).
// TM=32 nodes/block, thread (tx=tid&31, ty=tid>>5) owns 4 nodes x 4 cols.
// Software-pipelined: double-buffered LDS (A+W), register prefetch of chunk
// c+1 issued before computing chunk c, ONE __syncthreads per chunk.
// agg aliases out: each block reads only its own nodes' agg before writing.
// ---------------------------------------------------------------------------
__global__ __launch_bounds__(256) void gsage_main(
        const float* __restrict__ x,
        const float* __restrict__ agg,      // aliases `out`
        const float* __restrict__ Wt2,
        const float* __restrict__ cvec,
        const float* __restrict__ gamma,
        const float* __restrict__ beta,
        float* __restrict__ out)
{
    __shared__ float A[2][TM][APAD];   // 2 x 32 x 36 = 9.2 KB
    __shared__ float Wc[2][KB * 128];  // 2 x 16 KB

    int tid   = threadIdx.x;
    int tx    = tid & 31;
    int ty    = tid >> 5;
    int node0 = blockIdx.x * TM;

    int ar  = tid >> 3;              // A row 0..31
    int akk = (tid & 7) * 4;         // A k-offset within chunk
    int anode = node0 + ar;

    float acc[4][4];
    #pragma unroll
    for (int i = 0; i < 4; ++i)
        #pragma unroll
        for (int j = 0; j < 4; ++j) acc[i][j] = 0.0f;

    // ---- prologue: stage chunk 0 directly ----
    {
        float4 v = make_float4(0.f, 0.f, 0.f, 0.f);
        if (anode < N_NODES)
            v = *(const float4*)(x + (size_t)anode * D_FEAT + akk);
        *(float4*)&A[0][ar][akk] = v;
        const float4* src = (const float4*)Wt2;
        float4* dst = (float4*)Wc[0];
        #pragma unroll
        for (int i = 0; i < 4; ++i)
            dst[i * 256 + tid] = src[i * 256 + tid];
    }
    __syncthreads();

    for (int c = 0; c < 8; ++c) {
        int cur = c & 1, nxt = cur ^ 1;

        // ---- issue prefetch of chunk c+1 into registers ----
        float4 pa = make_float4(0.f, 0.f, 0.f, 0.f);
        float4 pw0, pw1, pw2, pw3;
        if (c < 7) {
            int k0n = (c + 1) * KB;
            if (anode < N_NODES) {
                const float* srcp = (k0n < 128)
                    ? (x   + (size_t)anode * D_FEAT + k0n + akk)
                    : (agg + (size_t)anode * D_FEAT + (k0n - 128) + akk);
                pa = *(const float4*)srcp;
            }
            const float4* src = (const float4*)(Wt2 + k0n * 128);
            pw0 = src[0 * 256 + tid];
            pw1 = src[1 * 256 + tid];
            pw2 = src[2 * 256 + tid];
            pw3 = src[3 * 256 + tid];
        }

        // ---- compute chunk c ----
        const float* Ab = &A[cur][0][0];
        const float* Wb = Wc[cur];
        #pragma unroll
        for (int kq = 0; kq < 8; ++kq) {
            float4 a0 = *(const float4*)(Ab + (ty * 4 + 0) * APAD + kq * 4);
            float4 a1 = *(const float4*)(Ab + (ty * 4 + 1) * APAD + kq * 4);
            float4 a2 = *(const float4*)(Ab + (ty * 4 + 2) * APAD + kq * 4);
            float4 a3 = *(const float4*)(Ab + (ty * 4 + 3) * APAD + kq * 4);
            const float* wbase = Wb + (kq * 4) * 128 + tx * 4;
            float4 w;
#define FMA_STEP(AX0, AX1, AX2, AX3)                                           \
            acc[0][0] += (AX0)*w.x; acc[0][1] += (AX0)*w.y;                    \
            acc[0][2] += (AX0)*w.z; acc[0][3] += (AX0)*w.w;                    \
            acc[1][0] += (AX1)*w.x; acc[1][1] += (AX1)*w.y;                    \
            acc[1][2] += (AX1)*w.z; acc[1][3] += (AX1)*w.w;                    \
            acc[2][0] += (AX2)*w.x; acc[2][1] += (AX2)*w.y;                    \
            acc[2][2] += (AX2)*w.z; acc[2][3] += (AX2)*w.w;                    \
            acc[3][0] += (AX3)*w.x; acc[3][1] += (AX3)*w.y;                    \
            acc[3][2] += (AX3)*w.z; acc[3][3] += (AX3)*w.w;
            w = *(const float4*)(wbase + 0 * 128); FMA_STEP(a0.x, a1.x, a2.x, a3.x)
            w = *(const float4*)(wbase + 1 * 128); FMA_STEP(a0.y, a1.y, a2.y, a3.y)
            w = *(const float4*)(wbase + 2 * 128); FMA_STEP(a0.z, a1.z, a2.z, a3.z)
            w = *(const float4*)(wbase + 3 * 128); FMA_STEP(a0.w, a1.w, a2.w, a3.w)
#undef FMA_STEP
        }

        // ---- commit prefetch into the other buffer ----
        if (c < 7) {
            *(float4*)&A[nxt][ar][akk] = pa;
            float4* dst = (float4*)Wc[nxt];
            dst[0 * 256 + tid] = pw0;
            dst[1 * 256 + tid] = pw1;
            dst[2 * 256 + tid] = pw2;
            dst[3 * 256 + tid] = pw3;
        }
        __syncthreads();
    }

    // ---- epilogue: +c, ReLU, LayerNorm over 128 cols (32 tx lanes) ----
    float4 cv = *(const float4*)(cvec  + tx * 4);
    float4 gv = *(const float4*)(gamma + tx * 4);
    float4 bv = *(const float4*)(beta  + tx * 4);

    #pragma unroll
    for (int i = 0; i < 4; ++i) {
        float v0 = acc[i][0] + cv.x; v0 = (v0 > 0.f) ? v0 : 0.f;
        float v1 = acc[i][1] + cv.y; v1 = (v1 > 0.f) ? v1 : 0.f;
        float v2 = acc[i][2] + cv.z; v2 = (v2 > 0.f) ? v2 : 0.f;
        float v3 = acc[i][3] + cv.w; v3 = (v3 > 0.f) ? v3 : 0.f;
        float s1 = v0 + v1 + v2 + v3;
        float s2 = v0*v0 + v1*v1 + v2*v2 + v3*v3;
        #pragma unroll
        for (int m = 1; m < 32; m <<= 1) {
            s1 += __shfl_xor(s1, m, 64);
            s2 += __shfl_xor(s2, m, 64);
        }
        float mu   = s1 * (1.0f / 128.0f);
        float var  = s2 * (1.0f / 128.0f) - mu * mu;
        float rstd = rsqrtf(var + LN_EPS);
        int node = node0 + ty * 4 + i;
        if (node < N_NODES) {
            float4 o;
            o.x = (v0 - mu) * rstd * gv.x + bv.x;
            o.y = (v1 - mu) * rstd * gv.y + bv.y;
            o.z = (v2 - mu) * rstd * gv.z + bv.z;
            o.w = (v3 - mu) * rstd * gv.w + bv.w;
            *(float4*)(out + (size_t)node * D_FEAT + tx * 4) = o;
        }
    }
}

// ---------------------------------------------------------------------------
extern "C" void kernel_launch(void* const* d_in, const int* in_sizes, int n_in,
                              void* d_out, int out_size, void* d_ws, size_t ws_size,
                              hipStream_t stream) {
    const float* x     = (const float*)d_in[0];
    const int*   ei    = (const int*)d_in[1];
    const float* agg_W = (const float*)d_in[2];
    const float* agg_b = (const float*)d_in[3];
    const float* W     = (const float*)d_in[4];
    const float* b     = (const float*)d_in[5];
    const float* gamma = (const float*)d_in[6];
    const float* beta  = (const float*)d_in[7];
    float*       out   = (float*)d_out;

    size_t out_bytes = (size_t)out_size * sizeof(float);

    if (n_in != 8)                       { hipMemsetAsync(d_out, 0x45, out_bytes, stream); return; }
    if (in_sizes[0] != N_NODES * D_FEAT) { hipMemsetAsync(d_out, 0x48, out_bytes, stream); return; }
    if (in_sizes[1] != 2 * N_EDGES)      { hipMemsetAsync(d_out, 0x49, out_bytes, stream); return; }
    if (out_size != N_NODES * D_FEAT)    { hipMemsetAsync(d_out, 0x47, out_bytes, stream); return; }

    // workspace layout (4-byte elements)
    int*   deg_cnt  = (int*)d_ws;                  // 50000
    int*   bsum     = deg_cnt + N_NODES;           // NBLK
    int*   boff     = bsum + NBLK;                 // NBLK
    int*   pos      = boff + NBLK;                 // 50000
    int*   edge_src = pos + N_NODES;               // 800000
    float* Wt2      = (float*)(edge_src + N_EDGES);// 256*128
    float* cvec     = Wt2 + 256 * 128;             // 128
    unsigned int* xh = (unsigned int*)(cvec + 128);// 50000*64 uints (bf16 x)
    size_t need_ws = ((size_t)N_NODES * 2 + N_EDGES + 256 * 128 + 128 + 2 * NBLK
                      + (size_t)N_NODES * 64) * 4;
    if (ws_size < need_ws)               { hipMemsetAsync(d_out, 0x46, out_bytes, stream); return; }

    hipMemsetAsync(deg_cnt, 0, N_NODES * sizeof(int), stream);
    prep_kernel<<<CVT_B + HIST_B + 128, 256, 0, stream>>>(
        x, ei, agg_W, agg_b, W, b, xh, deg_cnt, Wt2, cvec);
    blocksum_kernel<<<NBLK, 256, 0, stream>>>(deg_cnt, bsum);
    scanblk_kernel<<<1, 256, 0, stream>>>(bsum, boff);
    scanpos_kernel<<<NBLK, 256, 0, stream>>>(deg_cnt, boff, pos);
    fill_kernel<<<(N_EDGES + 255) / 256, 256, 0, stream>>>(ei, pos, edge_src);
    gather_kernel<<<(N_NODES + 3) / 4, 256, 0, stream>>>(
        (const uint4*)xh, pos, deg_cnt, edge_src, out);
    gsage_main<<<(N_NODES + TM - 1) / TM, 256, 0, stream>>>(
        x, out, Wt2, cvec, gamma, beta, out);
}

// Round 13
// 272.872 us; speedup vs baseline: 2.7368x; 1.1351x over previous
//
#include <hip/hip_runtime.h>

#define N_NODES 50000
#define N_EDGES 800000
#define D_FEAT 128
#define LN_EPS 1e-5f
#define TM 32          // nodes per block in gsage_main
#define KB 32          // K-chunk
#define APAD 36        // padded A-tile row stride (floats)
#define NBLK 196       // ceil(N_NODES/256) scan blocks
#define CVT_B 3125     // blocks for cvt range (800000 threads)
#define HIST_B 3125    // blocks for hist range

__device__ __forceinline__ unsigned short f2bf(float f) {
    union { float f; unsigned int i; } v; v.f = f;
    unsigned int x = v.i;
    unsigned int lsb = (x >> 16) & 1u;
    x += 0x7fffu + lsb;          // RNE
    return (unsigned short)(x >> 16);
}
__device__ __forceinline__ float bflo(unsigned int u) {
    union { unsigned int i; float f; } v; v.i = u << 16; return v.f;
}
__device__ __forceinline__ float bfhi(unsigned int u) {
    union { unsigned int i; float f; } v; v.i = u & 0xffff0000u; return v.f;
}

// ---------------------------------------------------------------------------
// prep kernel: block-range-split union of
//   [0, CVT_B)            : x fp32 -> xh bf16-packed
//   [CVT_B, CVT_B+HIST_B) : histogram of dst into deg_cnt (50K addresses;
//                           NEVER low-cardinality targets — R11: 800K atomics
//                           on 196 addresses serialized to ~400us)
//   [CVT_B+HIST_B, +128)  : wprep row t (fused weight + cvec)
// ---------------------------------------------------------------------------
__global__ void prep_kernel(const float* __restrict__ x,
                            const int* __restrict__ ei,
                            const float* __restrict__ agg_W,
                            const float* __restrict__ agg_b,
                            const float* __restrict__ W,
                            const float* __restrict__ b,
                            unsigned int* __restrict__ xh,
                            int* __restrict__ deg_cnt,
                            float* __restrict__ Wt2,
                            float* __restrict__ cvec)
{
    int blk = blockIdx.x;
    if (blk < CVT_B) {
        int i = blk * 256 + threadIdx.x;      // 800000 threads, 8 floats each
        const float4 a = *(const float4*)(x + (size_t)i * 8);
        const float4 c = *(const float4*)(x + (size_t)i * 8 + 4);
        uint4 o;
        o.x = ((unsigned)f2bf(a.y) << 16) | f2bf(a.x);
        o.y = ((unsigned)f2bf(a.w) << 16) | f2bf(a.z);
        o.z = ((unsigned)f2bf(c.y) << 16) | f2bf(c.x);
        o.w = ((unsigned)f2bf(c.w) << 16) | f2bf(c.z);
        *(uint4*)(xh + (size_t)i * 4) = o;
    } else if (blk < CVT_B + HIST_B) {
        int e = (blk - CVT_B) * 256 + threadIdx.x;
        if (e < N_EDGES) {
            int dst = ei[N_EDGES + e];
            dst = (dst < 0) ? 0 : ((dst >= N_NODES) ? (N_NODES - 1) : dst);
            atomicAdd(&deg_cnt[dst], 1);
        }
    } else {
        int t = blk - CVT_B - HIST_B;         // 0..127 (Wt2 row)
        int n = threadIdx.x;
        if (n < 128) {
            Wt2[t * 128 + n] = W[t * 128 + n];            // W1 half
            float m = 0.0f;
            for (int j = 0; j < 128; ++j)
                m += agg_W[t * 128 + j] * W[(128 + j) * 128 + n];
            Wt2[(128 + t) * 128 + n] = m;
            if (t == 0) {
                float s = b[n];
                for (int j = 0; j < 128; ++j)
                    s += agg_b[j] * W[(128 + j) * 128 + n];
                cvec[n] = s;
            }
        }
    }
}

// ---------------------------------------------------------------------------
// per-256-chunk sum of deg_cnt -> bsum (reduction, no atomics)
// ---------------------------------------------------------------------------
__global__ void blocksum_kernel(const int* __restrict__ deg_cnt, int* __restrict__ bsum)
{
    __shared__ int ws[4];
    int b = blockIdx.x, t = threadIdx.x;
    int i = b * 256 + t;
    int v = (i < N_NODES) ? deg_cnt[i] : 0;
    #pragma unroll
    for (int off = 1; off < 64; off <<= 1) v += __shfl_xor(v, off, 64);
    if ((t & 63) == 0) ws[t >> 6] = v;
    __syncthreads();
    if (t == 0) bsum[b] = ws[0] + ws[1] + ws[2] + ws[3];
}

// ---------------------------------------------------------------------------
// merged scan: every block (redundantly) scans the 196 chunk sums in LDS to
// get its own chunk offset, then does its block-local exclusive scan -> pos.
// ---------------------------------------------------------------------------
__global__ void scanpos_kernel(const int* __restrict__ deg_cnt,
                               const int* __restrict__ bsum,
                               int* __restrict__ pos)
{
    __shared__ int sb[256];
    __shared__ int s[256];
    int b = blockIdx.x, t = threadIdx.x;

    // scan of chunk sums (196 values) — cheap, done per block
    int vb = (t < NBLK) ? bsum[t] : 0;
    sb[t] = vb;
    __syncthreads();
    for (int off = 1; off < 256; off <<= 1) {
        int u = (t >= off) ? sb[t - off] : 0;
        __syncthreads();
        sb[t] += u;
        __syncthreads();
    }
    int boff = (b > 0) ? sb[b - 1] : 0;      // exclusive offset of this chunk

    int i = b * 256 + t;
    int v = (i < N_NODES) ? deg_cnt[i] : 0;
    s[t] = v;
    __syncthreads();
    for (int off = 1; off < 256; off <<= 1) {
        int u = (t >= off) ? s[t - off] : 0;
        __syncthreads();
        s[t] += u;
        __syncthreads();
    }
    if (i < N_NODES) pos[i] = boff + s[t] - v;   // exclusive global
}

// ---------------------------------------------------------------------------
__global__ void fill_kernel(const int* __restrict__ ei, int* __restrict__ pos,
                            int* __restrict__ edge_src)
{
    int e = blockIdx.x * 256 + threadIdx.x;
    if (e >= N_EDGES) return;
    int src = ei[e];
    int dst = ei[N_EDGES + e];
    src = (src < 0) ? 0 : ((src >= N_NODES) ? (N_NODES - 1) : src);
    dst = (dst < 0) ? 0 : ((dst >= N_NODES) ? (N_NODES - 1) : dst);
    int slot = atomicAdd(&pos[dst], 1);
    edge_src[slot] = src;
}

// ---------------------------------------------------------------------------
// gather: one wave per node, 4 edges per iteration (quarter-wave per edge,
// uint4 = 8 bf16 feats per lane). agg mean (fp32) written into d_out scratch.
// ---------------------------------------------------------------------------
__global__ void gather_kernel(const uint4* __restrict__ xh,   // 16 uint4 per row
                              const int* __restrict__ pos,    // = end after fill
                              const int* __restrict__ deg_cnt,
                              const int* __restrict__ edge_src,
                              float* __restrict__ agg)        // d_out scratch
{
    int tid  = threadIdx.x;
    int node = blockIdx.x * 4 + (tid >> 6);
    int lane = tid & 63;
    int quarter = lane >> 4;     // 0..3  (edge slot within iteration)
    int sub     = lane & 15;     // 0..15 (uint4 within row)
    if (node >= N_NODES) return;

    int end   = pos[node];
    int dcnt  = deg_cnt[node];
    int start = end - dcnt;

    float a0 = 0.f, a1 = 0.f, a2 = 0.f, a3 = 0.f,
          a4 = 0.f, a5 = 0.f, a6 = 0.f, a7 = 0.f;

    for (int b = start; b < end; b += 64) {
        int nb = end - b; if (nb > 64) nb = 64;
        int sid = (b + lane < end) ? edge_src[b + lane] : 0;
        for (int j = 0; j < nb; j += 4) {
            int eidx = j + quarter;
            int s = __shfl(sid, eidx, 64);
            if (eidx < nb) {
                const uint4 v = xh[(size_t)s * 16 + sub];
                a0 += bflo(v.x); a1 += bfhi(v.x);
                a2 += bflo(v.y); a3 += bfhi(v.y);
                a4 += bflo(v.z); a5 += bfhi(v.z);
                a6 += bflo(v.w); a7 += bfhi(v.w);
            }
        }
    }
    #pragma unroll
    for (int m = 16; m <= 32; m <<= 1) {
        a0 += __shfl_xor(a0, m, 64); a1 += __shfl_xor(a1, m, 64);
        a2 += __shfl_xor(a2, m, 64); a3 += __shfl_xor(a3, m, 64);
        a4 += __shfl_xor(a4, m, 64); a5 += __shfl_xor(a5, m, 64);
        a6 += __shfl_xor(a6, m, 64); a7 += __shfl_xor(a7, m, 64);
    }
    if (quarter == 0) {
        float inv = 1.0f / (float)((dcnt > 1) ? dcnt : 1);
        float4 m0, m1;
        m0.x = a0 * inv; m0.y = a1 * inv; m0.z = a2 * inv; m0.w = a3 * inv;
        m1.x = a4 * inv; m1.y = a5 * inv; m1.z = a6 * inv; m1.w = a7 * inv;
        float* dst = agg + (size_t)node * D_FEAT + sub * 8;
        *(float4*)dst       = m0;
        *(float4*)(dst + 4) = m1;
    }
}

// ---------------------------------------------------------------------------
// fused GEMM (A=[x|agg] @ Wt2^T + c) -> ReLU -> LayerNorm -> out (fp32).
// R8 structure (single buffer, 2 syncs/chunk, TM=32, 4x4 accs) with float4
// A-reads: per 4-k step 8 ds_read_b128 (~96 LDS cyc) vs 64 FMAs (128 VALU
// cyc) -> VALU-bound.  NO double-buffer / register prefetch (R12: occupancy
// collapse 9.4%, 97us).  agg aliases out (block-local read-before-write).
// ---------------------------------------------------------------------------
__global__ __launch_bounds__(256) void gsage_main(
        const float* __restrict__ x,
        const float* __restrict__ agg,      // aliases `out`
        const float* __restrict__ Wt2,
        const float* __restrict__ cvec,
        const float* __restrict__ gamma,
        const float* __restrict__ beta,
        float* __restrict__ out)
{
    __shared__ float A[TM][APAD];     // 32 x 36 = 4.6 KB
    __shared__ float Wc[KB * 128];    // 16 KB

    int tid   = threadIdx.x;
    int tx    = tid & 31;
    int ty    = tid >> 5;
    int node0 = blockIdx.x * TM;

    int ar  = tid >> 3;              // A staging row 0..31
    int akk = (tid & 7) * 4;         // A staging k-offset
    int anode = node0 + ar;

    float acc[4][4];
    #pragma unroll
    for (int i = 0; i < 4; ++i)
        #pragma unroll
        for (int j = 0; j < 4; ++j) acc[i][j] = 0.0f;

    for (int c = 0; c < 8; ++c) {
        int k0 = c * KB;
        // ---- stage A chunk (1 float4/thread) ----
        {
            float4 v = make_float4(0.f, 0.f, 0.f, 0.f);
            if (anode < N_NODES) {
                int k = k0 + akk;
                const float* src = (k < 128)
                    ? (x   + (size_t)anode * D_FEAT + k)
                    : (agg + (size_t)anode * D_FEAT + (k - 128));
                v = *(const float4*)src;
            }
            *(float4*)&A[ar][akk] = v;
        }
        // ---- stage W chunk (16 KB contiguous, 4 float4/thread) ----
        {
            const float4* src = (const float4*)(Wt2 + k0 * 128);
            float4* dstp = (float4*)Wc;
            #pragma unroll
            for (int i = 0; i < 4; ++i)
                dstp[i * 256 + tid] = src[i * 256 + tid];
        }
        __syncthreads();

        // ---- inner product: 4 k per step, float4 A-reads ----
        #pragma unroll
        for (int kq = 0; kq < 8; ++kq) {
            float4 a0 = *(const float4*)&A[ty * 4 + 0][kq * 4];
            float4 a1 = *(const float4*)&A[ty * 4 + 1][kq * 4];
            float4 a2 = *(const float4*)&A[ty * 4 + 2][kq * 4];
            float4 a3 = *(const float4*)&A[ty * 4 + 3][kq * 4];
            const float* wbase = Wc + (kq * 4) * 128 + tx * 4;
            float4 w;
#define FMA_STEP(AX0, AX1, AX2, AX3)                                           \
            acc[0][0] += (AX0)*w.x; acc[0][1] += (AX0)*w.y;                    \
            acc[0][2] += (AX0)*w.z; acc[0][3] += (AX0)*w.w;                    \
            acc[1][0] += (AX1)*w.x; acc[1][1] += (AX1)*w.y;                    \
            acc[1][2] += (AX1)*w.z; acc[1][3] += (AX1)*w.w;                    \
            acc[2][0] += (AX2)*w.x; acc[2][1] += (AX2)*w.y;                    \
            acc[2][2] += (AX2)*w.z; acc[2][3] += (AX2)*w.w;                    \
            acc[3][0] += (AX3)*w.x; acc[3][1] += (AX3)*w.y;                    \
            acc[3][2] += (AX3)*w.z; acc[3][3] += (AX3)*w.w;
            w = *(const float4*)(wbase + 0 * 128); FMA_STEP(a0.x, a1.x, a2.x, a3.x)
            w = *(const float4*)(wbase + 1 * 128); FMA_STEP(a0.y, a1.y, a2.y, a3.y)
            w = *(const float4*)(wbase + 2 * 128); FMA_STEP(a0.z, a1.z, a2.z, a3.z)
            w = *(const float4*)(wbase + 3 * 128); FMA_STEP(a0.w, a1.w, a2.w, a3.w)
#undef FMA_STEP
        }
        __syncthreads();
    }

    // ---- epilogue: +c, ReLU, LayerNorm over 128 cols (32 tx lanes) ----
    float4 cv = *(const float4*)(cvec  + tx * 4);
    float4 gv = *(const float4*)(gamma + tx * 4);
    float4 bv = *(const float4*)(beta  + tx * 4);

    #pragma unroll
    for (int i = 0; i < 4; ++i) {
        float v0 = acc[i][0] + cv.x; v0 = (v0 > 0.f) ? v0 : 0.f;
        float v1 = acc[i][1] + cv.y; v1 = (v1 > 0.f) ? v1 : 0.f;
        float v2 = acc[i][2] + cv.z; v2 = (v2 > 0.f) ? v2 : 0.f;
        float v3 = acc[i][3] + cv.w; v3 = (v3 > 0.f) ? v3 : 0.f;
        float s1 = v0 + v1 + v2 + v3;
        float s2 = v0*v0 + v1*v1 + v2*v2 + v3*v3;
        #pragma unroll
        for (int m = 1; m < 32; m <<= 1) {
            s1 += __shfl_xor(s1, m, 64);
            s2 += __shfl_xor(s2, m, 64);
        }
        float mu   = s1 * (1.0f / 128.0f);
        float var  = s2 * (1.0f / 128.0f) - mu * mu;
        float rstd = rsqrtf(var + LN_EPS);
        int node = node0 + ty * 4 + i;
        if (node < N_NODES) {
            float4 o;
            o.x = (v0 - mu) * rstd * gv.x + bv.x;
            o.y = (v1 - mu) * rstd * gv.y + bv.y;
            o.z = (v2 - mu) * rstd * gv.z + bv.z;
            o.w = (v3 - mu) * rstd * gv.w + bv.w;
            *(float4*)(out + (size_t)node * D_FEAT + tx * 4) = o;
        }
    }
}

// ---------------------------------------------------------------------------
extern "C" void kernel_launch(void* const* d_in, const int* in_sizes, int n_in,
                              void* d_out, int out_size, void* d_ws, size_t ws_size,
                              hipStream_t stream) {
    const float* x     = (const float*)d_in[0];
    const int*   ei    = (const int*)d_in[1];
    const float* agg_W = (const float*)d_in[2];
    const float* agg_b = (const float*)d_in[3];
    const float* W     = (const float*)d_in[4];
    const float* b     = (const float*)d_in[5];
    const float* gamma = (const float*)d_in[6];
    const float* beta  = (const float*)d_in[7];
    float*       out   = (float*)d_out;

    size_t out_bytes = (size_t)out_size * sizeof(float);

    if (n_in != 8)                       { hipMemsetAsync(d_out, 0x45, out_bytes, stream); return; }
    if (in_sizes[0] != N_NODES * D_FEAT) { hipMemsetAsync(d_out, 0x48, out_bytes, stream); return; }
    if (in_sizes[1] != 2 * N_EDGES)      { hipMemsetAsync(d_out, 0x49, out_bytes, stream); return; }
    if (out_size != N_NODES * D_FEAT)    { hipMemsetAsync(d_out, 0x47, out_bytes, stream); return; }

    // workspace layout (4-byte elements)
    int*   deg_cnt  = (int*)d_ws;                  // 50000
    int*   bsum     = deg_cnt + N_NODES;           // NBLK
    int*   pos      = bsum + NBLK;                 // 50000
    int*   edge_src = pos + N_NODES;               // 800000
    float* Wt2      = (float*)(edge_src + N_EDGES);// 256*128
    float* cvec     = Wt2 + 256 * 128;             // 128
    unsigned int* xh = (unsigned int*)(cvec + 128);// 50000*64 uints (bf16 x)
    size_t need_ws = ((size_t)N_NODES * 2 + N_EDGES + 256 * 128 + 128 + NBLK
                      + (size_t)N_NODES * 64) * 4;
    if (ws_size < need_ws)               { hipMemsetAsync(d_out, 0x46, out_bytes, stream); return; }

    hipMemsetAsync(deg_cnt, 0, N_NODES * sizeof(int), stream);
    prep_kernel<<<CVT_B + HIST_B + 128, 256, 0, stream>>>(
        x, ei, agg_W, agg_b, W, b, xh, deg_cnt, Wt2, cvec);
    blocksum_kernel<<<NBLK, 256, 0, stream>>>(deg_cnt, bsum);
    scanpos_kernel<<<NBLK, 256, 0, stream>>>(deg_cnt, bsum, pos);
    fill_kernel<<<(N_EDGES + 255) / 256, 256, 0, stream>>>(ei, pos, edge_src);
    gather_kernel<<<(N_NODES + 3) / 4, 256, 0, stream>>>(
        (const uint4*)xh, pos, deg_cnt, edge_src, out);
    gsage_main<<<(N_NODES + TM - 1) / TM, 256, 0, stream>>>(
        x, out, Wt2, cvec, gamma, beta, out);
}